// Round 19
// baseline (217.985 us; speedup 1.0000x reference)
//
#include <hip/hip_runtime.h>

typedef __attribute__((ext_vector_type(8))) short short8;
typedef __attribute__((ext_vector_type(4))) float f32x4;

// Problem dims
#define BDIM 4096
#define INDIM 1024
#define HDIM 2048
#define KDIM 3072   // IN + H
#define NDIM 8192   // 4*H
#define OUT_HALF 8388608  // 4096*2048
#define NKT 96      // K-tiles of 32
#define ACHUNKS 1572864

__device__ __forceinline__ unsigned short f2bf(float f) {
  unsigned u = __float_as_uint(f);
  u += 0x7FFFu + ((u >> 16) & 1u);
  return (unsigned short)(u >> 16);
}

__device__ __forceinline__ float sigmoidf_(float x) {
  return 1.0f / (1.0f + __expf(-x));
}

// Merged pack: A = [x|h] bf16 [4096][3072]; W' gate-interleaved bf16 [8192][3072];
// bias[n'] = b_ih + b_hh.  (At HBM roofline: 224 MB compulsory.)
__global__ __launch_bounds__(256) void pack_all(
    const float* __restrict__ x, const float* __restrict__ hh,
    const float* __restrict__ w_ih, const float* __restrict__ w_hh,
    const float* __restrict__ b_ih, const float* __restrict__ b_hh,
    unsigned short* __restrict__ A, unsigned short* __restrict__ W,
    float* __restrict__ bias) {
  int idx = blockIdx.x * 256 + threadIdx.x;
  if (idx < ACHUNKS) {
    int m = idx / 384;
    int k0 = (idx - m * 384) * 8;
    const float* src = (k0 < INDIM) ? (x + (size_t)m * INDIM + k0)
                                    : (hh + (size_t)m * HDIM + (k0 - INDIM));
    float4 lo = ((const float4*)src)[0];
    float4 hi = ((const float4*)src)[1];
    union { unsigned short us[8]; uint4 v; } o;
    o.us[0] = f2bf(lo.x); o.us[1] = f2bf(lo.y); o.us[2] = f2bf(lo.z); o.us[3] = f2bf(lo.w);
    o.us[4] = f2bf(hi.x); o.us[5] = f2bf(hi.y); o.us[6] = f2bf(hi.z); o.us[7] = f2bf(hi.w);
    *(uint4*)(A + (size_t)m * KDIM + k0) = o.v;
  } else {
    idx -= ACHUNKS;
    int np = idx / 384;
    int rem = idx - np * 384;
    int k0 = rem * 8;
    int j = np >> 2;
    int g = np & 3;
    int n = g * HDIM + j;
    const float* src = (k0 < INDIM) ? (w_ih + (size_t)n * INDIM + k0)
                                    : (w_hh + (size_t)n * HDIM + (k0 - INDIM));
    float4 lo = ((const float4*)src)[0];
    float4 hi = ((const float4*)src)[1];
    union { unsigned short us[8]; uint4 v; } o;
    o.us[0] = f2bf(lo.x); o.us[1] = f2bf(lo.y); o.us[2] = f2bf(lo.z); o.us[3] = f2bf(lo.w);
    o.us[4] = f2bf(hi.x); o.us[5] = f2bf(hi.y); o.us[6] = f2bf(hi.z); o.us[7] = f2bf(hi.w);
    *(uint4*)(W + (size_t)np * KDIM + k0) = o.v;
    if (rem == 0) bias[np] = b_ih[n] + b_hh[n];
  }
}

__device__ __forceinline__ void gload_lds16(const void* g, void* l) {
  __builtin_amdgcn_global_load_lds(
      (const __attribute__((address_space(1))) void*)g,
      (__attribute__((address_space(3))) void*)l, 16, 0, 0);
}

#define SB0 __builtin_amdgcn_sched_barrier(0)

// R10-exact GEMM K-loop (best of 12 measured structures): 256x256 tile,
// BK=32, 8 waves (2Mx4N), 4-deep LDS ring (4 x 32KiB), row-pair XOR swizzle
// (T2), counted vmcnt (T4), setprio (T5), 1-barrier-per-K-tile pipelined
// schedule. Epilogue: vectorized consumer + mi-parity double-buffered LDS
// bounce (no trailing fence -> mi iterations pipeline; c-load issued early).
__global__ __launch_bounds__(512, 2) void lstm_gemm(
    const unsigned short* __restrict__ A,
    const unsigned short* __restrict__ W,
    const float* __restrict__ bias,
    const float* __restrict__ c,
    float* __restrict__ out) {
  extern __shared__ char smem[];  // 131072 bytes

  const int tid = threadIdx.x;
  const int lane = tid & 63;
  const int wid = tid >> 6;

  // XCD swizzle: xcd owns 2 tm slabs; tn sweeps slowest. Bijective over 512.
  const int bid = blockIdx.x;
  const int local = bid >> 3;
  const int tm = (bid & 7) * 2 + (local & 1);   // 0..15
  const int tn = local >> 1;                    // 0..31

  // ---- staging source decode (inverse swizzle, rule #21) ----
  int rowA0, clA0, rowA1, clA1;
  {
    int P0 = wid * 1024 + lane * 16;
    int P1 = 8192 + wid * 1024 + lane * 16;
    int r2, cp, cg;
    r2 = P0 >> 7; cp = (P0 >> 4) & 7; cg = cp ^ (r2 & 7);
    rowA0 = r2 * 2 + (cg >> 2); clA0 = cg & 3;
    r2 = P1 >> 7; cp = (P1 >> 4) & 7; cg = cp ^ (r2 & 7);
    rowA1 = r2 * 2 + (cg >> 2); clA1 = cg & 3;
  }
  const unsigned short* gA0 = A + (size_t)(tm * 256 + rowA0) * KDIM + clA0 * 8;
  const unsigned short* gA1 = A + (size_t)(tm * 256 + rowA1) * KDIM + clA1 * 8;
  const unsigned short* gB0 = W + (size_t)(tn * 256 + rowA0) * KDIM + clA0 * 8;
  const unsigned short* gB1 = W + (size_t)(tn * 256 + rowA1) * KDIM + clA1 * 8;
  const int ldA0 = wid * 1024;
  const int ldA1 = 8192 + wid * 1024;
  const int ldB0 = 16384 + wid * 1024;
  const int ldB1 = 24576 + wid * 1024;

  // ---- ds_read per-lane constants (swizzled) ----
  const int fr = lane & 15;
  const int fq = lane >> 4;
  const int wr = wid >> 2;    // 0..1 (rows)
  const int wc = wid & 3;     // 0..3 (cols)
  const int frh = fr >> 1;
  const int clA = (((fr & 1) << 2) | fq) ^ frh;
  const int aconst = wr * 8192 + frh * 128 + clA * 16;
  const int bconst = 16384 + wc * 4096 + frh * 128 + clA * 16;

  f32x4 acc[8][4] = {};
  short8 af[4], bf_[4], ag[4];

  // ---- prologue: stage tiles 0,1,2 ----
#pragma unroll
  for (int tt = 0; tt < 3; ++tt) {
    char* lb = smem + tt * 32768;
    gload_lds16(gA0, lb + ldA0);
    gload_lds16(gA1, lb + ldA1);
    gload_lds16(gB0, lb + ldB0);
    gload_lds16(gB1, lb + ldB1);
    gA0 += 32; gA1 += 32; gB0 += 32; gB1 += 32;
  }
  asm volatile("s_waitcnt vmcnt(8)" ::: "memory");   // tile 0 landed
  __builtin_amdgcn_s_barrier(); SB0;
  // issue af(0), bf_(0)
#pragma unroll
  for (int mi = 0; mi < 4; ++mi)
    af[mi] = *(const short8*)(smem + aconst + mi * 1024);
#pragma unroll
  for (int ni = 0; ni < 4; ++ni)
    bf_[ni] = *(const short8*)(smem + bconst + ni * 1024);

// Tile body. Entry: af(T),bf_(T) issued; vm queue = stages for T+1,T+2 (8).
#define TILE_BODY(T, VMSTR, STAGE_, PREF_)                                   \
  do {                                                                       \
    const char* rb = smem + ((T) & 3) * 32768;                               \
    const char* rbn = smem + (((T) + 1) & 3) * 32768;                        \
    char* lb = smem + (((T) + 3) & 3) * 32768;                               \
    if (STAGE_) {                                                            \
      gload_lds16(gA0, lb + ldA0);                                           \
      gload_lds16(gA1, lb + ldA1);                                           \
    }                                                                        \
    _Pragma("unroll")                                                        \
    for (int mi = 0; mi < 4; ++mi)                                           \
      ag[mi] = *(const short8*)(rb + aconst + (mi + 4) * 1024);              \
    SB0;                                                                     \
    __builtin_amdgcn_s_setprio(1);                                           \
    _Pragma("unroll")                                                        \
    for (int mi = 0; mi < 4; ++mi)                                           \
      _Pragma("unroll")                                                      \
      for (int ni = 0; ni < 4; ++ni)                                         \
        acc[mi][ni] = __builtin_amdgcn_mfma_f32_16x16x32_bf16(               \
            af[mi], bf_[ni], acc[mi][ni], 0, 0, 0);                          \
    __builtin_amdgcn_s_setprio(0);                                           \
    if (STAGE_) {                                                            \
      gload_lds16(gB0, lb + ldB0);                                           \
      gload_lds16(gB1, lb + ldB1);                                           \
      gA0 += 32; gA1 += 32; gB0 += 32; gB1 += 32;                            \
    }                                                                        \
    asm volatile("s_waitcnt vmcnt(" VMSTR ")" ::: "memory");                 \
    asm volatile("s_waitcnt lgkmcnt(0)" ::: "memory");                       \
    __builtin_amdgcn_s_barrier(); SB0;                                       \
    if (PREF_) {                                                             \
      _Pragma("unroll")                                                      \
      for (int mi = 0; mi < 4; ++mi)                                         \
        af[mi] = *(const short8*)(rbn + aconst + mi * 1024);                 \
    }                                                                        \
    SB0;                                                                     \
    __builtin_amdgcn_s_setprio(1);                                           \
    _Pragma("unroll")                                                        \
    for (int mi = 0; mi < 4; ++mi)                                           \
      _Pragma("unroll")                                                      \
      for (int ni = 0; ni < 4; ++ni)                                         \
        acc[mi + 4][ni] = __builtin_amdgcn_mfma_f32_16x16x32_bf16(           \
            ag[mi], bf_[ni], acc[mi + 4][ni], 0, 0, 0);                      \
    __builtin_amdgcn_s_setprio(0);                                           \
    if (PREF_) {                                                             \
      _Pragma("unroll")                                                      \
      for (int ni = 0; ni < 4; ++ni)                                         \
        bf_[ni] = *(const short8*)(rbn + bconst + ni * 1024);                \
    }                                                                        \
  } while (0)

  for (int t = 0; t < NKT - 3; ++t) TILE_BODY(t, "8", true, true);
  TILE_BODY(NKT - 3, "4", false, true);
  TILE_BODY(NKT - 2, "0", false, true);
  TILE_BODY(NKT - 1, "0", false, false);
#undef TILE_BODY

  // ---- fused LSTM epilogue (vectorized, mi-parity double-buffered) ----
  // Two wave-private bounce regions (ep0/ep1, 36864 B each, total 73728 B
  // in bufs 0-2; final K-tile read only buf 3). No trailing fence: next mi
  // writes the OTHER region, so its c-load + ep-writes overlap this mi's
  // math and stores.
  const int rsel = lane >> 2;
  const int jsel = lane & 3;
  const int jgb = tn * 64 + wc * 16 + jsel * 4;   // first of 4 global j
  f32x4 bi4[4];
#pragma unroll
  for (int q = 0; q < 4; ++q)
    bi4[q] = *(const f32x4*)(bias + tn * 256 + wc * 64 + (jsel * 4 + q) * 4);
  float* ep0 = (float*)smem + wid * 1152;
  float* ep1 = (float*)smem + 9216 + wid * 1152;

#pragma unroll
  for (int mi = 0; mi < 8; ++mi) {
    float* ep = (mi & 1) ? ep1 : ep0;
    const int mg = tm * 256 + wr * 128 + mi * 16 + rsel;
    const f32x4 cv = *(const f32x4*)(c + (size_t)mg * HDIM + jgb);  // early
#pragma unroll
    for (int ni = 0; ni < 4; ++ni)
#pragma unroll
      for (int r = 0; r < 4; ++r)
        ep[(fq * 4 + r) * 68 + ni * 16 + fr] = acc[mi][ni][r];
    asm volatile("s_waitcnt lgkmcnt(0)" ::: "memory");
    f32x4 g[4];
#pragma unroll
    for (int q = 0; q < 4; ++q)
      g[q] = *(const f32x4*)(ep + rsel * 68 + (jsel * 4 + q) * 4);
    f32x4 ht4, ct4;
#pragma unroll
    for (int q = 0; q < 4; ++q) {
      const float f_in = g[q][0] + bi4[q][0];
      const float i_in = g[q][1] + bi4[q][1];
      const float ic_in = g[q][2] + bi4[q][2];
      const float o_in = g[q][3] + bi4[q][3];
      const float ft = sigmoidf_(f_in);
      const float it = sigmoidf_(i_in);
      const float ics = __sinf(ic_in);
      const float ct = cv[q] * ft + ics * it;
      const float ot = sigmoidf_(o_in);
      ht4[q] = ot * __sinf(ct);
      ct4[q] = ct;
    }
    *(f32x4*)(out + (size_t)mg * HDIM + jgb) = ht4;
    *(f32x4*)(out + OUT_HALF + (size_t)mg * HDIM + jgb) = ct4;
  }
}

extern "C" void kernel_launch(void* const* d_in, const int* in_sizes, int n_in,
                              void* d_out, int out_size, void* d_ws, size_t ws_size,
                              hipStream_t stream) {
  const float* x    = (const float*)d_in[0];
  const float* h    = (const float*)d_in[1];
  const float* c    = (const float*)d_in[2];
  const float* w_ih = (const float*)d_in[3];
  const float* w_hh = (const float*)d_in[4];
  const float* b_ih = (const float*)d_in[5];
  const float* b_hh = (const float*)d_in[6];
  float* out = (float*)d_out;

  char* ws = (char*)d_ws;
  unsigned short* Abf = (unsigned short*)ws;                       // 25,165,824 B
  unsigned short* Wbf = (unsigned short*)(ws + 25165824);          // 50,331,648 B
  float* bias = (float*)(ws + 25165824 + 50331648);                // 32,768 B

  hipFuncSetAttribute((const void*)lstm_gemm,
                      hipFuncAttributeMaxDynamicSharedMemorySize, 131072);

  pack_all<<<18432, 256, 0, stream>>>(x, h, w_ih, w_hh, b_ih, b_hh, Abf, Wbf, bias);
  lstm_gemm<<<512, 512, 131072, stream>>>(Abf, Wbf, bias, c, out);
}